// Round 9
// baseline (9227.219 us; speedup 1.0000x reference)
//
#include <hip/hip_runtime.h>

// Problem constants
#define B_    32
#define T_    2048
#define F_    64
#define H_    256
#define OUT_  64
#define G3_   768           // 3*H
#define NWG1  16            // layer-1 pipeline WGs
#define NWG2  16            // layer-2 pipeline WGs
#define TOTAL_WG (NWG1 + NWG2)
#define WGT   512           // threads per WG (8 waves)

// Stamped pack: u32[par][bb(32)][w(16)][jl(16)], each u32 = (gen+1)<<16 | fp16.
// Row (bb,w) = 64B = one cache line. h1 depth 4, h2 depth 2.
#define ROWI(par, bb, w) ((((par) * 32 + (bb)) * 16 + (w)) * 16)
#define S1_U32 (4 * 32 * 16 * 16)                // 32768 u32 = 128 KB
#define S2_U32 (2 * 32 * 16 * 16)                // 16384 u32 =  64 KB

// ws layout (bytes)
#define XN_BYTES (B_ * T_ * F_ * 2)              // 8,388,608 fp16 LN(x), [T][B][F]
#define S1_OFF   XN_BYTES
#define S2_OFF   (S1_OFF + S1_U32 * 4)
#define PROG_OFF (S2_OFF + S2_U32 * 4)           // 16 lines x 64B (L2 progress)

typedef _Float16 half8 __attribute__((ext_vector_type(8)));
typedef _Float16 half4 __attribute__((ext_vector_type(4)));
typedef float    f32x4 __attribute__((ext_vector_type(4)));
typedef unsigned u32x4 __attribute__((ext_vector_type(4)));
typedef unsigned long long u64;

#define LD_A(p)    __hip_atomic_load((p),  __ATOMIC_RELAXED, __HIP_MEMORY_SCOPE_AGENT)
#define ST_A(p, v) __hip_atomic_store((p), (v), __ATOMIC_RELAXED, __HIP_MEMORY_SCOPE_AGENT)

__device__ __forceinline__ float sigf(float x) {
    x = fminf(fmaxf(x, -30.f), 30.f);
    return 1.f / (1.f + __expf(-x));
}
__device__ __forceinline__ float tanhfast(float x) {
    x = fminf(fmaxf(x, -15.f), 15.f);
    float e = __expf(2.f * x);
    return (e - 1.f) / (e + 1.f);
}
__device__ __forceinline__ unsigned short f16b(float f) {
    union { _Float16 h; unsigned short u; } c; c.h = (_Float16)f; return c.u;
}

// ---------------------------------------------------------------------------
// Init: zero stamped packs (stamp 0 = gen -1 = h[-1] = 0) + prog, out = bias
// ---------------------------------------------------------------------------
__global__ void init_kernel(float* __restrict__ out, const float* __restrict__ bd,
                            unsigned* __restrict__ s1) {
    int t = blockIdx.x * 256 + threadIdx.x;              // 4096 threads
    if (t < B_ * OUT_) out[t] = bd[t & (OUT_ - 1)];
    for (int p = t; p < S1_U32 + S2_U32 + 256; p += 4096) s1[p] = 0u;
}

// ---------------------------------------------------------------------------
// LayerNorm over F=64, fp16 output TRANSPOSED to [T][B][F].
// ---------------------------------------------------------------------------
__global__ __launch_bounds__(256) void ln_kernel(const float* __restrict__ x,
                                                 const float* __restrict__ gamma,
                                                 const float* __restrict__ beta,
                                                 _Float16* __restrict__ xn) {
    const int tid = threadIdx.x;
    const int r = tid >> 4, q = tid & 15;
    const size_t row = (size_t)blockIdx.x * 16 + r;      // = b*T + t
    const int b = (int)(row >> 11);
    const int t = (int)(row & 2047);
    const float4 v  = *(const float4*)(x + row * F_ + q * 4);
    const float4 g  = *(const float4*)(gamma + q * 4);
    const float4 be = *(const float4*)(beta + q * 4);
    float s = v.x + v.y + v.z + v.w;
    s += __shfl_xor(s, 1, 16); s += __shfl_xor(s, 2, 16);
    s += __shfl_xor(s, 4, 16); s += __shfl_xor(s, 8, 16);
    const float mu = s * (1.f / 64.f);
    const float dx = v.x - mu, dy = v.y - mu, dz = v.z - mu, dw = v.w - mu;
    float qq = dx * dx + dy * dy + dz * dz + dw * dw;
    qq += __shfl_xor(qq, 1, 16); qq += __shfl_xor(qq, 2, 16);
    qq += __shfl_xor(qq, 4, 16); qq += __shfl_xor(qq, 8, 16);
    const float rs = rsqrtf(qq * (1.f / 64.f) + 1e-3f);
    half4 o;
    o[0] = (_Float16)(dx * rs * g.x + be.x);
    o[1] = (_Float16)(dy * rs * g.y + be.y);
    o[2] = (_Float16)(dz * rs * g.z + be.z);
    o[3] = (_Float16)(dw * rs * g.w + be.w);
    *(half4*)(xn + ((size_t)t * B_ + b) * F_ + q * 4) = o;
}

// ---------------------------------------------------------------------------
// Dual-pipeline persistent GRU, stamped fire-and-forget handoff.
// WGs 0..15 (L1): h1 chain. Publish = stamped u64 atomic stores, NO drain,
//   NO flag. Consumers poll their own 64B source row (stamps==gen validate).
// WGs 16..31 (L2): h2 chain, one step behind; stages h1[t] + h2[t-1] the
//   same way; posts prog[w]=t+1 (off-critical) for L1 depth-4 back-pressure.
// ---------------------------------------------------------------------------
__global__ __launch_bounds__(WGT) void gru_main(
    const _Float16* __restrict__ xn,
    const float* __restrict__ k1, const float* __restrict__ rk1,
    const float* __restrict__ b1, const float* __restrict__ k2,
    const float* __restrict__ rk2, const float* __restrict__ b2,
    const float* __restrict__ wd, float* __restrict__ out,
    unsigned* __restrict__ s1, unsigned* __restrict__ s2,
    unsigned* __restrict__ prog) {
    const int tid  = threadIdx.x;
    const int lane = tid & 63;
    const int wave = tid >> 6;           // 8 waves
    const int mt   = wave & 1;
    const int nt   = wave >> 1;          // 0..3
    const int ln   = lane & 15;
    const int quad = lane >> 4;

    __shared__ _Float16 h1s[32][264];    // 528B rows
    __shared__ _Float16 h2s[32][264];
    __shared__ float Cs[2][32][52];
    __shared__ float hs[32][16];

    const int  lc    = nt * 16 + ln;
    const bool valid = (lc < 48);
    const int  gate  = lc >> 4;
    const int  hidx  = lc & 15;
    const int  jl    = tid & 15;
    const int  bb    = tid >> 4;         // 0..31
    const int  m     = mt * 16 + ln;     // batch row for A fragments
    const int  w2    = tid & 15;         // staging source WG

    if (blockIdx.x < NWG1) {
        // ================= L1 pipeline =================
        const int w    = blockIdx.x;
        const int gcol = valid ? (gate * H_ + w * 16 + hidx) : 0;
        half8 fk1[2], frk1[8];
#pragma unroll
        for (int ks = 0; ks < 2; ++ks) {
            half8 f;
#pragma unroll
            for (int j = 0; j < 8; ++j) {
                const float v = k1[(ks * 32 + quad * 8 + j) * G3_ + gcol];
                f[j] = valid ? (_Float16)v : (_Float16)0.f;
            }
            fk1[ks] = f;
        }
#pragma unroll
        for (int ks = 0; ks < 8; ++ks) {
            half8 f;
#pragma unroll
            for (int j = 0; j < 8; ++j) {
                const float v = rk1[(ks * 32 + quad * 8 + j) * G3_ + gcol];
                f[j] = valid ? (_Float16)v : (_Float16)0.f;
            }
            frk1[ks] = f;
        }
        const int gc = w * 16 + jl;
        const float bxz = b1[gc],       bxr = b1[H_ + gc],       bxh = b1[2 * H_ + gc];
        const float bhz = b1[G3_ + gc], bhr = b1[G3_ + H_ + gc], bhh = b1[G3_ + 2 * H_ + gc];
        float h1m = 0.f;
        const unsigned* f2p = prog + w2 * 16;      // L2 progress (back-pressure)

        for (int i = 0; i < T_; ++i) {
            // xproj (no cross-WG dep) before polling
            f32x4 c0 = {0.f, 0.f, 0.f, 0.f};
            {
                half8 ax0 = *(const half8*)(xn + ((size_t)i * B_ + m) * F_ + quad * 8);
                half8 ax1 = *(const half8*)(xn + ((size_t)i * B_ + m) * F_ + 32 + quad * 8);
                c0 = __builtin_amdgcn_mfma_f32_16x16x32_f16(ax0, fk1[0], c0, 0, 0, 0);
                c0 = __builtin_amdgcn_mfma_f32_16x16x32_f16(ax1, fk1[1], c0, 0, 0, 0);
            }
            // depth-4 back-pressure (slack 3; almost always pre-satisfied)
            if (i >= 4) {
                const unsigned tg2 = (unsigned)(i - 3);
                while (LD_A(f2p) < tg2) __builtin_amdgcn_s_sleep(1);
            }
            // stamped poll+stage of own source row: h1[i-1], stamp == i
            {
                const unsigned tgt = (unsigned)i;
                const u64* row = (const u64*)(s1 + ROWI((i + 3) & 3, bb, w2));
                u64 q[8];
                for (;;) {
#pragma unroll
                    for (int k = 0; k < 8; ++k) q[k] = LD_A(row + k);
                    unsigned bad = 0;
#pragma unroll
                    for (int k = 0; k < 8; ++k) bad |= (unsigned)(q[k] >> 48) ^ tgt;
                    if (bad == 0) break;
                    __builtin_amdgcn_s_sleep(1);
                }
                unsigned pk[8];
#pragma unroll
                for (int k = 0; k < 8; ++k)
                    pk[k] = ((unsigned)q[k] & 0xffffu) |
                            (((unsigned)(q[k] >> 32) & 0xffffu) << 16);
                u32x4 va, vb;
                va[0] = pk[0]; va[1] = pk[1]; va[2] = pk[2]; va[3] = pk[3];
                vb[0] = pk[4]; vb[1] = pk[5]; vb[2] = pk[6]; vb[3] = pk[7];
                *(u32x4*)(&h1s[bb][w2 * 16])     = va;
                *(u32x4*)(&h1s[bb][w2 * 16 + 8]) = vb;
            }
            __syncthreads();

            f32x4 c1 = {0.f, 0.f, 0.f, 0.f};
#pragma unroll
            for (int ks = 0; ks < 8; ++ks) {
                half8 a1 = *(const half8*)(&h1s[m][ks * 32 + quad * 8]);
                c1 = __builtin_amdgcn_mfma_f32_16x16x32_f16(a1, frk1[ks], c1, 0, 0, 0);
            }
            if (valid) {
                const int r0 = mt * 16 + quad * 4;
#pragma unroll
                for (int rr = 0; rr < 4; ++rr) {
                    Cs[0][r0 + rr][lc] = c0[rr];
                    Cs[1][r0 + rr][lc] = c1[rr];
                }
            }
            __syncthreads();

            // gates + fire-and-forget stamped publish of h1[i] (stamp i+1)
            {
                const float xz = Cs[0][bb][jl]      + bxz;
                const float xr = Cs[0][bb][16 + jl] + bxr;
                const float xh = Cs[0][bb][32 + jl] + bxh;
                const float rz = Cs[1][bb][jl]      + bhz;
                const float rr = Cs[1][bb][16 + jl] + bhr;
                const float rh = Cs[1][bb][32 + jl] + bhh;
                const float z  = sigf(xz + rz);
                const float r  = sigf(xr + rr);
                const float hh = tanhfast(xh + r * rh);
                h1m = z * h1m + (1.f - z) * hh;
                const unsigned val = (((unsigned)(i + 1)) << 16) | f16b(h1m);
                const unsigned pr  = (unsigned)__shfl_xor((int)val, 1);
                if (!(jl & 1))
                    ST_A((u64*)(s1 + ROWI(i & 3, bb, w) + jl),
                         (u64)val | ((u64)pr << 32));
            }
        }
    } else {
        // ================= L2 pipeline =================
        const int w    = blockIdx.x - NWG1;
        const int gcol = valid ? (gate * H_ + w * 16 + hidx) : 0;
        half8 fk2[8], frk2[8];
#pragma unroll
        for (int ks = 0; ks < 8; ++ks) {
            half8 f2, f3;
#pragma unroll
            for (int j = 0; j < 8; ++j) {
                const int k = ks * 32 + quad * 8 + j;
                const float v2 = k2 [k * G3_ + gcol];
                const float v3 = rk2[k * G3_ + gcol];
                f2[j] = valid ? (_Float16)v2 : (_Float16)0.f;
                f3[j] = valid ? (_Float16)v3 : (_Float16)0.f;
            }
            fk2[ks] = f2; frk2[ks] = f3;
        }
        const int gc = w * 16 + jl;
        const float bxz = b2[gc],       bxr = b2[H_ + gc],       bxh = b2[2 * H_ + gc];
        const float bhz = b2[G3_ + gc], bhr = b2[G3_ + H_ + gc], bhh = b2[G3_ + 2 * H_ + gc];
        float h2m = 0.f;

        for (int t = 0; t < T_; ++t) {
            // stamped poll+stage: h1[t] (stamp t+1) and h2[t-1] (stamp t)
            {
                const unsigned tg1 = (unsigned)(t + 1);
                const unsigned tg2 = (unsigned)t;
                const u64* r1 = (const u64*)(s1 + ROWI(t & 3, bb, w2));
                const u64* r2 = (const u64*)(s2 + ROWI((t + 1) & 1, bb, w2));
                u64 q1[8], q2[8];
                for (;;) {
#pragma unroll
                    for (int k = 0; k < 8; ++k) q1[k] = LD_A(r1 + k);
#pragma unroll
                    for (int k = 0; k < 8; ++k) q2[k] = LD_A(r2 + k);
                    unsigned bad = 0;
#pragma unroll
                    for (int k = 0; k < 8; ++k) bad |= (unsigned)(q1[k] >> 48) ^ tg1;
#pragma unroll
                    for (int k = 0; k < 8; ++k) bad |= (unsigned)(q2[k] >> 48) ^ tg2;
                    if (bad == 0) break;
                    __builtin_amdgcn_s_sleep(1);
                }
                unsigned p1k[8], p2k[8];
#pragma unroll
                for (int k = 0; k < 8; ++k) {
                    p1k[k] = ((unsigned)q1[k] & 0xffffu) |
                             (((unsigned)(q1[k] >> 32) & 0xffffu) << 16);
                    p2k[k] = ((unsigned)q2[k] & 0xffffu) |
                             (((unsigned)(q2[k] >> 32) & 0xffffu) << 16);
                }
                u32x4 a0, a1, b0, b1v;
                a0[0] = p1k[0]; a0[1] = p1k[1]; a0[2] = p1k[2]; a0[3] = p1k[3];
                a1[0] = p1k[4]; a1[1] = p1k[5]; a1[2] = p1k[6]; a1[3] = p1k[7];
                b0[0] = p2k[0]; b0[1] = p2k[1]; b0[2] = p2k[2]; b0[3] = p2k[3];
                b1v[0] = p2k[4]; b1v[1] = p2k[5]; b1v[2] = p2k[6]; b1v[3] = p2k[7];
                *(u32x4*)(&h1s[bb][w2 * 16])     = a0;
                *(u32x4*)(&h1s[bb][w2 * 16 + 8]) = a1;
                *(u32x4*)(&h2s[bb][w2 * 16])     = b0;
                *(u32x4*)(&h2s[bb][w2 * 16 + 8]) = b1v;
            }
            __syncthreads();
            if (tid == 0) ST_A(&prog[w * 16], (unsigned)(t + 1));  // staged h1[t]

            f32x4 c2 = {0.f, 0.f, 0.f, 0.f};
            f32x4 c3 = c2;
#pragma unroll
            for (int ks = 0; ks < 8; ++ks) {
                half8 a1 = *(const half8*)(&h1s[m][ks * 32 + quad * 8]);
                half8 a2 = *(const half8*)(&h2s[m][ks * 32 + quad * 8]);
                c2 = __builtin_amdgcn_mfma_f32_16x16x32_f16(a1, fk2[ks],  c2, 0, 0, 0);
                c3 = __builtin_amdgcn_mfma_f32_16x16x32_f16(a2, frk2[ks], c3, 0, 0, 0);
            }
            if (valid) {
                const int r0 = mt * 16 + quad * 4;
#pragma unroll
                for (int rr = 0; rr < 4; ++rr) {
                    Cs[0][r0 + rr][lc] = c2[rr];
                    Cs[1][r0 + rr][lc] = c3[rr];
                }
            }
            __syncthreads();

            // gates + fire-and-forget stamped publish of h2[t] (stamp t+1)
            {
                const float xz = Cs[0][bb][jl]      + bxz;
                const float xr = Cs[0][bb][16 + jl] + bxr;
                const float xh = Cs[0][bb][32 + jl] + bxh;
                const float rz = Cs[1][bb][jl]      + bhz;
                const float rr = Cs[1][bb][16 + jl] + bhr;
                const float rh = Cs[1][bb][32 + jl] + bhh;
                const float z  = sigf(xz + rz);
                const float r  = sigf(xr + rr);
                const float hh = tanhfast(xh + r * rh);
                h2m = z * h2m + (1.f - z) * hh;
                const unsigned val = (((unsigned)(t + 1)) << 16) | f16b(h2m);
                const unsigned pr  = (unsigned)__shfl_xor((int)val, 1);
                if (!(jl & 1))
                    ST_A((u64*)(s2 + ROWI(t & 1, bb, w) + jl),
                         (u64)val | ((u64)pr << 32));
            }
        }

        // ---- final dense: out[b][o] += sum_j h2[b][16w+j] * wd[16w+j][o]
        hs[bb][jl] = h2m;                // h2m = h2[T-1]
        __syncthreads();
        const int o  = tid & 63;
        const int bq = tid >> 6;         // 0..7
        for (int pass = 0; pass < 4; ++pass) {
            const int b = pass * 8 + bq;
            float acc = 0.f;
#pragma unroll
            for (int j = 0; j < 16; ++j) acc += hs[b][j] * wd[(w * 16 + j) * OUT_ + o];
            atomicAdd(&out[b * OUT_ + o], acc);
        }
    }
}

// ---------------------------------------------------------------------------
extern "C" void kernel_launch(void* const* d_in, const int* in_sizes, int n_in,
                              void* d_out, int out_size, void* d_ws, size_t ws_size,
                              hipStream_t stream) {
    const float* x     = (const float*)d_in[0];
    const float* gamma = (const float*)d_in[1];
    const float* beta  = (const float*)d_in[2];
    const float* k1    = (const float*)d_in[3];
    const float* rk1   = (const float*)d_in[4];
    const float* b1    = (const float*)d_in[5];
    const float* k2    = (const float*)d_in[6];
    const float* rk2   = (const float*)d_in[7];
    const float* b2    = (const float*)d_in[8];
    const float* wd    = (const float*)d_in[9];
    const float* bd    = (const float*)d_in[10];
    float* out = (float*)d_out;

    char* ws = (char*)d_ws;
    _Float16* xn   = (_Float16*)ws;
    unsigned* s1   = (unsigned*)(ws + S1_OFF);
    unsigned* s2   = (unsigned*)(ws + S2_OFF);
    unsigned* prog = (unsigned*)(ws + PROG_OFF);

    hipLaunchKernelGGL(init_kernel, dim3(16), dim3(256), 0, stream, out, bd, s1);
    hipLaunchKernelGGL(ln_kernel, dim3(B_ * T_ / 16), dim3(256), 0, stream, x, gamma, beta, xn);

    void* args[] = {(void*)&xn, (void*)&k1, (void*)&rk1, (void*)&b1, (void*)&k2,
                    (void*)&rk2, (void*)&b2, (void*)&wd, (void*)&out,
                    (void*)&s1, (void*)&s2, (void*)&prog};
    hipLaunchCooperativeKernel((void*)gru_main, dim3(TOTAL_WG), dim3(WGT), args, 0, stream);
}

// Round 10
// 5518.933 us; speedup vs baseline: 1.6719x; 1.6719x over previous
//
#include <hip/hip_runtime.h>

// Problem constants
#define B_    32
#define T_    2048
#define F_    64
#define H_    256
#define OUT_  64
#define G3_   768           // 3*H
#define NWG1  16            // layer-1 pipeline WGs
#define NWG2  16            // layer-2 pipeline WGs
#define TOTAL_WG (NWG1 + NWG2)
#define WGT   512           // threads per WG (8 waves)

// Source-major packs: fp16 [par][w(16)][bb(32)][16 cols]; 1 KB contiguous per
// (par, w). h1 depth 4 (64 KB), h2 depth 2 (32 KB).
#define PBLK   512                               // halfs per (par,w) block
#define XN_BYTES (B_ * T_ * F_ * 2)              // 8,388,608 fp16 LN(x), [T][B][F]
#define S1_OFF   XN_BYTES                        // 65536 B
#define S2_OFF   (S1_OFF + 4 * 16 * PBLK * 2)    // +64 KB
#define FLAG_OFF (S2_OFF + 2 * 16 * PBLK * 2)    // +32 KB; flags: 32 lines x 64B
#define PROG_OFF (FLAG_OFF + 2048)               // prog: 16 lines x 64B

typedef _Float16 half8 __attribute__((ext_vector_type(8)));
typedef _Float16 half4 __attribute__((ext_vector_type(4)));
typedef float    f32x4 __attribute__((ext_vector_type(4)));
typedef unsigned long long u64;

#define LD_A(p)    __hip_atomic_load((p),  __ATOMIC_RELAXED, __HIP_MEMORY_SCOPE_AGENT)
#define ST_A(p, v) __hip_atomic_store((p), (v), __ATOMIC_RELAXED, __HIP_MEMORY_SCOPE_AGENT)

__device__ __forceinline__ float sigf(float x) {
    x = fminf(fmaxf(x, -30.f), 30.f);
    return 1.f / (1.f + __expf(-x));
}
__device__ __forceinline__ float tanhfast(float x) {
    x = fminf(fmaxf(x, -15.f), 15.f);
    float e = __expf(2.f * x);
    return (e - 1.f) / (e + 1.f);
}
__device__ __forceinline__ unsigned short f16b(float f) {
    union { _Float16 h; unsigned short u; } c; c.h = (_Float16)f; return c.u;
}
// Gather 4 neighboring lanes' fp16 (jl, jl^1, jl^2, jl^3) into one u64 (LE by jl)
__device__ __forceinline__ u64 gather4(unsigned short u, int jl) {
    unsigned int p = (unsigned int)__shfl_xor((int)(unsigned int)u, 1);
    unsigned int lo32 = (jl & 1) ? ((p & 0xffffu) | ((unsigned int)u << 16))
                                 : ((unsigned int)u | (p << 16));
    unsigned int q = (unsigned int)__shfl_xor((int)lo32, 2);
    return (jl & 2) ? (((u64)lo32 << 32) | q)
                    : ((u64)lo32 | ((u64)q << 32));
}

// ---------------------------------------------------------------------------
// Init: zero packs + flags + prog, out = bias broadcast
// ---------------------------------------------------------------------------
__global__ void init_kernel(float* __restrict__ out, const float* __restrict__ bd,
                            _Float16* __restrict__ packs, unsigned int* __restrict__ flg) {
    int t = blockIdx.x * 256 + threadIdx.x;              // 4096 threads
    if (t < B_ * OUT_) out[t] = bd[t & (OUT_ - 1)];
    if (t < 1024) flg[t] = 0u;                           // flags (512 dw) + prog (256 dw) + pad
    for (int p = t; p < 6 * 16 * PBLK; p += 4096) packs[p] = (_Float16)0.f;
}

// ---------------------------------------------------------------------------
// LayerNorm over F=64, fp16 output TRANSPOSED to [T][B][F].
// ---------------------------------------------------------------------------
__global__ __launch_bounds__(256) void ln_kernel(const float* __restrict__ x,
                                                 const float* __restrict__ gamma,
                                                 const float* __restrict__ beta,
                                                 _Float16* __restrict__ xn) {
    const int tid = threadIdx.x;
    const int r = tid >> 4, q = tid & 15;
    const size_t row = (size_t)blockIdx.x * 16 + r;      // = b*T + t
    const int b = (int)(row >> 11);
    const int t = (int)(row & 2047);
    const float4 v  = *(const float4*)(x + row * F_ + q * 4);
    const float4 g  = *(const float4*)(gamma + q * 4);
    const float4 be = *(const float4*)(beta + q * 4);
    float s = v.x + v.y + v.z + v.w;
    s += __shfl_xor(s, 1, 16); s += __shfl_xor(s, 2, 16);
    s += __shfl_xor(s, 4, 16); s += __shfl_xor(s, 8, 16);
    const float mu = s * (1.f / 64.f);
    const float dx = v.x - mu, dy = v.y - mu, dz = v.z - mu, dw = v.w - mu;
    float qq = dx * dx + dy * dy + dz * dz + dw * dw;
    qq += __shfl_xor(qq, 1, 16); qq += __shfl_xor(qq, 2, 16);
    qq += __shfl_xor(qq, 4, 16); qq += __shfl_xor(qq, 8, 16);
    const float rs = rsqrtf(qq * (1.f / 64.f) + 1e-3f);
    half4 o;
    o[0] = (_Float16)(dx * rs * g.x + be.x);
    o[1] = (_Float16)(dy * rs * g.y + be.y);
    o[2] = (_Float16)(dz * rs * g.z + be.z);
    o[3] = (_Float16)(dw * rs * g.w + be.w);
    *(half4*)(xn + ((size_t)t * B_ + b) * F_ + q * 4) = o;
}

// ---------------------------------------------------------------------------
// Dual-pipeline persistent GRU, source-major packs, coalesced handoff.
// WGs 0..15  (L1): h1 chain, publishes 1 KB contiguous block per step.
// WGs 16..31 (L2): h2 chain (lag 1), stages h1[t] + h2[t-1], posts prog.
// Protocol identical to R8 (drain -> sync -> tid0 flag; narrow per-source
// polls); only the pack layout / staging access pattern changed.
// ---------------------------------------------------------------------------
__global__ __launch_bounds__(WGT) void gru_main(
    const _Float16* __restrict__ xn,
    const float* __restrict__ k1, const float* __restrict__ rk1,
    const float* __restrict__ b1, const float* __restrict__ k2,
    const float* __restrict__ rk2, const float* __restrict__ b2,
    const float* __restrict__ wd, float* __restrict__ out,
    _Float16* __restrict__ p1, _Float16* __restrict__ p2,
    unsigned int* __restrict__ flags, unsigned int* __restrict__ prog) {
    const int tid  = threadIdx.x;
    const int lane = tid & 63;
    const int wave = tid >> 6;           // 8 waves
    const int mt   = wave & 1;
    const int nt   = wave >> 1;          // 0..3
    const int ln   = lane & 15;
    const int quad = lane >> 4;

    __shared__ _Float16 h1s[32][264];    // 528B rows
    __shared__ _Float16 h2s[32][264];
    __shared__ float Cs[2][32][52];
    __shared__ float hs[32][16];

    const int  lc    = nt * 16 + ln;
    const bool valid = (lc < 48);
    const int  gate  = lc >> 4;
    const int  hidx  = lc & 15;
    const int  jl    = tid & 15;
    const int  bb    = tid >> 4;         // 0..31
    const int  m     = mt * 16 + ln;     // batch row for A fragments

    if (blockIdx.x < NWG1) {
        // ================= L1 pipeline =================
        const int w    = blockIdx.x;
        const int gcol = valid ? (gate * H_ + w * 16 + hidx) : 0;
        half8 fk1[2], frk1[8];
#pragma unroll
        for (int ks = 0; ks < 2; ++ks) {
            half8 f;
#pragma unroll
            for (int j = 0; j < 8; ++j) {
                const float v = k1[(ks * 32 + quad * 8 + j) * G3_ + gcol];
                f[j] = valid ? (_Float16)v : (_Float16)0.f;
            }
            fk1[ks] = f;
        }
#pragma unroll
        for (int ks = 0; ks < 8; ++ks) {
            half8 f;
#pragma unroll
            for (int j = 0; j < 8; ++j) {
                const float v = rk1[(ks * 32 + quad * 8 + j) * G3_ + gcol];
                f[j] = valid ? (_Float16)v : (_Float16)0.f;
            }
            frk1[ks] = f;
        }
        const int gc = w * 16 + jl;
        const float bxz = b1[gc],       bxr = b1[H_ + gc],       bxh = b1[2 * H_ + gc];
        const float bhz = b1[G3_ + gc], bhr = b1[G3_ + H_ + gc], bhh = b1[G3_ + 2 * H_ + gc];
        float h1m = 0.f;

        // staging map: 32 threads per source WG, contiguous 1 KB block
        const int w2  = tid >> 5;                  // source WG 0..15
        const int t32 = tid & 31;
        const unsigned* f1p = flags + w2 * 16;     // h1flag[w2]
        const unsigned* f2p = prog  + w2 * 16;     // L2 progress (back-pressure)

        for (int i = 0; i < T_; ++i) {
            // xproj (no cross-WG dep) before polling
            f32x4 c0 = {0.f, 0.f, 0.f, 0.f};
            {
                half8 ax0 = *(const half8*)(xn + ((size_t)i * B_ + m) * F_ + quad * 8);
                half8 ax1 = *(const half8*)(xn + ((size_t)i * B_ + m) * F_ + 32 + quad * 8);
                c0 = __builtin_amdgcn_mfma_f32_16x16x32_f16(ax0, fk1[0], c0, 0, 0, 0);
                c0 = __builtin_amdgcn_mfma_f32_16x16x32_f16(ax1, fk1[1], c0, 0, 0, 0);
            }
            // poll own source flag + back-pressure, then coalesced 1 KB stage
            {
                const unsigned tgt1 = (unsigned)i;
                const unsigned tgt2 = (i >= 4) ? (unsigned)(i - 3) : 0u;
                while (LD_A(f1p) < tgt1 || LD_A(f2p) < tgt2)
                    __builtin_amdgcn_s_sleep(1);
                // block base: parity (i-1)&3 == (i+3)&3, source w2
                const u64* src = (const u64*)(p1 + (((unsigned)(i + 3) & 3u) * 16 + w2) * PBLK);
                u64 q0 = LD_A(src + t32);
                u64 q1 = LD_A(src + 32 + t32);
                u64 q2 = LD_A(src + 64 + t32);
                u64 q3 = LD_A(src + 96 + t32);
                const int b0 = t32 >> 2;           // bb for k=0
                const int c0f = w2 * 16 + (t32 & 3) * 4;
                *(u64*)(&h1s[b0][c0f])      = q0;
                *(u64*)(&h1s[b0 + 8][c0f])  = q1;
                *(u64*)(&h1s[b0 + 16][c0f]) = q2;
                *(u64*)(&h1s[b0 + 24][c0f]) = q3;
            }
            __syncthreads();

            f32x4 c1 = {0.f, 0.f, 0.f, 0.f};
#pragma unroll
            for (int ks = 0; ks < 8; ++ks) {
                half8 a1 = *(const half8*)(&h1s[m][ks * 32 + quad * 8]);
                c1 = __builtin_amdgcn_mfma_f32_16x16x32_f16(a1, frk1[ks], c1, 0, 0, 0);
            }
            if (valid) {
                const int r0 = mt * 16 + quad * 4;
#pragma unroll
                for (int rr = 0; rr < 4; ++rr) {
                    Cs[0][r0 + rr][lc] = c0[rr];
                    Cs[1][r0 + rr][lc] = c1[rr];
                }
            }
            __syncthreads();

            // gates + publish h1[i] into own contiguous block
            {
                const float xz = Cs[0][bb][jl]      + bxz;
                const float xr = Cs[0][bb][16 + jl] + bxr;
                const float xh = Cs[0][bb][32 + jl] + bxh;
                const float rz = Cs[1][bb][jl]      + bhz;
                const float rr = Cs[1][bb][16 + jl] + bhr;
                const float rh = Cs[1][bb][32 + jl] + bhh;
                const float z  = sigf(xz + rz);
                const float r  = sigf(xr + rr);
                const float hh = tanhfast(xh + r * rh);
                h1m = z * h1m + (1.f - z) * hh;
                const u64 v1 = gather4(f16b(h1m), jl);
                if ((jl & 3) == 0)
                    ST_A((u64*)(p1 + ((unsigned)(i & 3) * 16 + w) * PBLK + bb * 16 + jl), v1);
                asm volatile("s_waitcnt vmcnt(0)" ::: "memory");
            }
            __syncthreads();
            if (tid == 0) ST_A(&flags[w * 16], (unsigned)(i + 1));
        }
    } else {
        // ================= L2 pipeline =================
        const int w    = blockIdx.x - NWG1;
        const int gcol = valid ? (gate * H_ + w * 16 + hidx) : 0;
        half8 fk2[8], frk2[8];
#pragma unroll
        for (int ks = 0; ks < 8; ++ks) {
            half8 f2, f3;
#pragma unroll
            for (int j = 0; j < 8; ++j) {
                const int k = ks * 32 + quad * 8 + j;
                const float v2 = k2 [k * G3_ + gcol];
                const float v3 = rk2[k * G3_ + gcol];
                f2[j] = valid ? (_Float16)v2 : (_Float16)0.f;
                f3[j] = valid ? (_Float16)v3 : (_Float16)0.f;
            }
            fk2[ks] = f2; frk2[ks] = f3;
        }
        const int gc = w * 16 + jl;
        const float bxz = b2[gc],       bxr = b2[H_ + gc],       bxh = b2[2 * H_ + gc];
        const float bhz = b2[G3_ + gc], bhr = b2[G3_ + H_ + gc], bhh = b2[G3_ + 2 * H_ + gc];
        float h2m = 0.f;

        // staging map: pk 0 = h1[t] (256 thr), pk 1 = h2[t-1] (256 thr);
        // 16 threads per source, 64 B each, contiguous
        const int pk  = tid >> 8;
        const int tt  = tid & 255;
        const int w2  = tt >> 4;
        const int l16 = tt & 15;
        const unsigned* fp = pk ? (flags + (16 + w2) * 16) : (flags + w2 * 16);

        for (int t = 0; t < T_; ++t) {
            // poll own source, coalesced stage of its 1 KB block slice
            {
                const unsigned tgt = pk ? (unsigned)t : (unsigned)(t + 1);
                while (LD_A(fp) < tgt) __builtin_amdgcn_s_sleep(1);
                const u64* src = pk
                    ? (const u64*)(p2 + (((unsigned)(t + 1) & 1u) * 16 + w2) * PBLK)
                    : (const u64*)(p1 + (((unsigned)t & 3u) * 16 + w2) * PBLK);
                u64 q[8];
#pragma unroll
                for (int k = 0; k < 8; ++k) q[k] = LD_A(src + k * 16 + l16);
                _Float16 (*dst)[264] = pk ? h2s : h1s;
                const int c0f = w2 * 16 + (l16 & 3) * 4;
                const int b0  = l16 >> 2;          // bb for k=0
#pragma unroll
                for (int k = 0; k < 8; ++k)
                    *(u64*)(&dst[b0 + k * 4][c0f]) = q[k];
            }
            __syncthreads();
            if (tid == 0) ST_A(&prog[w * 16], (unsigned)(t + 1));  // staged h1[t]

            f32x4 c2 = {0.f, 0.f, 0.f, 0.f};
            f32x4 c3 = c2;
#pragma unroll
            for (int ks = 0; ks < 8; ++ks) {
                half8 a1 = *(const half8*)(&h1s[m][ks * 32 + quad * 8]);
                half8 a2 = *(const half8*)(&h2s[m][ks * 32 + quad * 8]);
                c2 = __builtin_amdgcn_mfma_f32_16x16x32_f16(a1, fk2[ks],  c2, 0, 0, 0);
                c3 = __builtin_amdgcn_mfma_f32_16x16x32_f16(a2, frk2[ks], c3, 0, 0, 0);
            }
            if (valid) {
                const int r0 = mt * 16 + quad * 4;
#pragma unroll
                for (int rr = 0; rr < 4; ++rr) {
                    Cs[0][r0 + rr][lc] = c2[rr];
                    Cs[1][r0 + rr][lc] = c3[rr];
                }
            }
            __syncthreads();

            // gates + publish h2[t] into own contiguous block
            {
                const float xz = Cs[0][bb][jl]      + bxz;
                const float xr = Cs[0][bb][16 + jl] + bxr;
                const float xh = Cs[0][bb][32 + jl] + bxh;
                const float rz = Cs[1][bb][jl]      + bhz;
                const float rr = Cs[1][bb][16 + jl] + bhr;
                const float rh = Cs[1][bb][32 + jl] + bhh;
                const float z  = sigf(xz + rz);
                const float r  = sigf(xr + rr);
                const float hh = tanhfast(xh + r * rh);
                h2m = z * h2m + (1.f - z) * hh;
                const u64 v2 = gather4(f16b(h2m), jl);
                if ((jl & 3) == 0)
                    ST_A((u64*)(p2 + ((unsigned)(t & 1) * 16 + w) * PBLK + bb * 16 + jl), v2);
                asm volatile("s_waitcnt vmcnt(0)" ::: "memory");
            }
            __syncthreads();
            if (tid == 0) ST_A(&flags[(16 + w) * 16], (unsigned)(t + 1));
        }

        // ---- final dense: out[b][o] += sum_j h2[b][16w+j] * wd[16w+j][o]
        hs[bb][jl] = h2m;                // h2m = h2[T-1]
        __syncthreads();
        const int o  = tid & 63;
        const int bq = tid >> 6;         // 0..7
        for (int pass = 0; pass < 4; ++pass) {
            const int b = pass * 8 + bq;
            float acc = 0.f;
#pragma unroll
            for (int j = 0; j < 16; ++j) acc += hs[b][j] * wd[(w * 16 + j) * OUT_ + o];
            atomicAdd(&out[b * OUT_ + o], acc);
        }
    }
}

// ---------------------------------------------------------------------------
extern "C" void kernel_launch(void* const* d_in, const int* in_sizes, int n_in,
                              void* d_out, int out_size, void* d_ws, size_t ws_size,
                              hipStream_t stream) {
    const float* x     = (const float*)d_in[0];
    const float* gamma = (const float*)d_in[1];
    const float* beta  = (const float*)d_in[2];
    const float* k1    = (const float*)d_in[3];
    const float* rk1   = (const float*)d_in[4];
    const float* b1    = (const float*)d_in[5];
    const float* k2    = (const float*)d_in[6];
    const float* rk2   = (const float*)d_in[7];
    const float* b2    = (const float*)d_in[8];
    const float* wd    = (const float*)d_in[9];
    const float* bd    = (const float*)d_in[10];
    float* out = (float*)d_out;

    char* ws = (char*)d_ws;
    _Float16*     xn    = (_Float16*)ws;
    _Float16*     p1    = (_Float16*)(ws + S1_OFF);
    _Float16*     p2    = (_Float16*)(ws + S2_OFF);
    unsigned int* flags = (unsigned int*)(ws + FLAG_OFF);
    unsigned int* prog  = (unsigned int*)(ws + PROG_OFF);

    hipLaunchKernelGGL(init_kernel, dim3(16), dim3(256), 0, stream, out, bd, p1, flags);
    hipLaunchKernelGGL(ln_kernel, dim3(B_ * T_ / 16), dim3(256), 0, stream, x, gamma, beta, xn);

    void* args[] = {(void*)&xn, (void*)&k1, (void*)&rk1, (void*)&b1, (void*)&k2,
                    (void*)&rk2, (void*)&b2, (void*)&wd, (void*)&out,
                    (void*)&p1, (void*)&p2, (void*)&flags, (void*)&prog};
    hipLaunchCooperativeKernel((void*)gru_main, dim3(TOTAL_WG), dim3(WGT), args, 0, stream);
}